// Round 4
// baseline (234.201 us; speedup 1.0000x reference)
//
#include <hip/hip_runtime.h>
#include <hip/hip_bf16.h>
#include <math.h>

// Problem constants
#define T_TOK 8192   // B*S tokens
#define DIM   512    // D
#define NEXP  8      // E
#define HID   2048   // H
#define NBAT  8      // B
#define SEQ   1024   // S

typedef short  short8 __attribute__((ext_vector_type(8)));
typedef float  f32x4  __attribute__((ext_vector_type(4)));

__device__ __forceinline__ unsigned short f2bf(float f) {
    union { float f; unsigned int u; } v; v.f = f;
    unsigned int u = v.u;
    unsigned int r = u + 0x7FFFu + ((u >> 16) & 1u);  // RNE
    return (unsigned short)(r >> 16);
}

// ---------------- w1 [E][D][H] fp32 -> w1t [E][H][D] bf16 (vectorized) ----------------
__global__ void transpose_w1_k(const float* __restrict__ w1, unsigned short* __restrict__ w1t) {
    __shared__ unsigned short tile[64][65];
    int d0 = blockIdx.x * 64, h0 = blockIdx.y * 64, e = blockIdx.z;
    int tid = threadIdx.x;
    const float* src = w1 + (size_t)e * DIM * HID;
    #pragma unroll
    for (int pass = 0; pass < 4; ++pass) {
        int dr = pass * 16 + (tid >> 4);
        int hc = (tid & 15) * 4;
        float4 v = *(const float4*)(src + (size_t)(d0 + dr) * HID + h0 + hc);
        tile[hc + 0][dr] = f2bf(v.x);
        tile[hc + 1][dr] = f2bf(v.y);
        tile[hc + 2][dr] = f2bf(v.z);
        tile[hc + 3][dr] = f2bf(v.w);
    }
    __syncthreads();
    unsigned short* dst = w1t + (size_t)e * HID * DIM;
    #pragma unroll
    for (int pass = 0; pass < 4; ++pass) {
        int hr = pass * 16 + (tid >> 4);
        int dc = (tid & 15) * 4;
        ushort4 o;
        o.x = tile[hr][dc];     o.y = tile[hr][dc + 1];
        o.z = tile[hr][dc + 2]; o.w = tile[hr][dc + 3];
        *(ushort4*)(dst + (size_t)(h0 + hr) * DIM + d0 + dc) = o;
    }
}

// ---------------- w2sum[e][h] = sum_d w2[e][h][d]; last block also does b2sum ----------------
__global__ void w2b2_k(const float* __restrict__ w2, const float* __restrict__ b2,
                       float* __restrict__ w2sum, float* __restrict__ b2sum) {
    int wave = threadIdx.x >> 6, lane = threadIdx.x & 63;
    if (blockIdx.x < NEXP * HID / 4) {
        int row = blockIdx.x * 4 + wave;
        const float* p = w2 + (size_t)row * DIM;
        float4 a = *(const float4*)(p + lane * 4);
        float4 b = *(const float4*)(p + 256 + lane * 4);
        float s = a.x + a.y + a.z + a.w + b.x + b.y + b.z + b.w;
        #pragma unroll
        for (int off = 32; off >= 1; off >>= 1) s += __shfl_xor(s, off);
        if (lane == 0) w2sum[row] = s;
    } else {
        for (int r = wave; r < NEXP; r += 4) {
            const float* p = b2 + (size_t)r * DIM;
            float s = 0.f;
            for (int i = lane; i < DIM; i += 64) s += p[i];
            #pragma unroll
            for (int off = 32; off >= 1; off >>= 1) s += __shfl_xor(s, off);
            if (lane == 0) b2sum[r] = s;
        }
    }
}

// ---------------- gating + fused x->bf16 cast: NO atomics ----------------
__global__ void gate2_k(const float* __restrict__ x, const float* __restrict__ gw,
                        const float* __restrict__ gb, const float* __restrict__ b2sum,
                        unsigned short* __restrict__ xb,
                        int* __restrict__ eidx, float* __restrict__ esc0,
                        float* __restrict__ esc1, float* __restrict__ s_partial) {
    int wave = threadIdx.x >> 6, lane = threadIdx.x & 63;
    int t = blockIdx.x * 4 + wave;
    const float* xp = x + (size_t)t * DIM;
    unsigned short* xbp = xb + (size_t)t * DIM;
    float acc[8] = {0, 0, 0, 0, 0, 0, 0, 0};
    #pragma unroll
    for (int it = 0; it < 8; ++it) {
        int d = it * 64 + lane;
        float xv = xp[d];
        xbp[d] = f2bf(xv);
        float4 g0 = *(const float4*)(gw + d * 8);
        float4 g1 = *(const float4*)(gw + d * 8 + 4);
        acc[0] += xv * g0.x; acc[1] += xv * g0.y; acc[2] += xv * g0.z; acc[3] += xv * g0.w;
        acc[4] += xv * g1.x; acc[5] += xv * g1.y; acc[6] += xv * g1.z; acc[7] += xv * g1.w;
    }
    #pragma unroll
    for (int e = 0; e < 8; ++e) {
        float s = acc[e];
        #pragma unroll
        for (int off = 32; off >= 1; off >>= 1) s += __shfl_xor(s, off);
        acc[e] = s + gb[e];
    }
    float v0 = -1e30f, v1 = -1e30f; int i0 = 0, i1 = 0;
    #pragma unroll
    for (int e = 0; e < 8; ++e) {
        float v = acc[e];
        if (v > v0) { v1 = v0; i1 = i0; v0 = v; i0 = e; }
        else if (v > v1) { v1 = v; i1 = e; }
    }
    float e1 = expf(v1 - v0);
    float inv = 1.f / (1.f + e1);
    float s0 = inv, s1 = e1 * inv;
    if (lane == 0) {
        eidx[t] = i0 | (i1 << 4);
        esc0[t] = s0;
        esc1[t] = s1;
        s_partial[t] = s0 * b2sum[i0] + s1 * b2sum[i1];
    }
}

// ---------------- routing: ballot-rank within wave, LDS across waves, 8 atomics/block ----------------
__global__ __launch_bounds__(1024) void route_k(
    const int* __restrict__ eidx, const float* __restrict__ esc0,
    const float* __restrict__ esc1, int* __restrict__ counts,
    int* __restrict__ ptok, float* __restrict__ pscore) {
    int tid = threadIdx.x;
    int t = blockIdx.x * 1024 + tid;
    int wv = tid >> 6, lane = tid & 63;
    int pk = eidx[t];
    int i0 = pk & 0xf, i1 = (pk >> 4) & 0xf;
    float s0 = esc0[t], s1 = esc1[t];

    __shared__ int waveCnt[16][8];
    __shared__ int waveBase[16][8];

    unsigned long long m0[8], m1[8];
    #pragma unroll
    for (int e = 0; e < 8; ++e) {
        m0[e] = __ballot(i0 == e);
        m1[e] = __ballot(i1 == e);
    }
    if (lane < 8) {
        int c = 0;
        #pragma unroll
        for (int e = 0; e < 8; ++e)
            if (lane == e) c = __popcll(m0[e]) + __popcll(m1[e]);
        waveCnt[wv][lane] = c;
    }
    __syncthreads();
    if (tid < 8) {
        int e = tid;
        int total = 0;
        #pragma unroll
        for (int w = 0; w < 16; ++w) total += waveCnt[w][e];
        int base = atomicAdd(&counts[e], total);
        int run = base;
        #pragma unroll
        for (int w = 0; w < 16; ++w) {
            waveBase[w][e] = run;
            run += waveCnt[w][e];
        }
    }
    __syncthreads();

    unsigned long long lt = (1ULL << lane) - 1ULL;
    int slot0 = 0, slot1 = 0;
    #pragma unroll
    for (int e = 0; e < 8; ++e) {
        if (i0 == e) slot0 = waveBase[wv][e] + __popcll(m0[e] & lt);
        if (i1 == e) slot1 = waveBase[wv][e] + __popcll(m0[e]) + __popcll(m1[e] & lt);
    }
    ptok[i0 * T_TOK + slot0] = t;  pscore[i0 * T_TOK + slot0] = s0;
    ptok[i1 * T_TOK + slot1] = t;  pscore[i1 * T_TOK + slot1] = s1;
}

// ---------------- tile list: compact (expert, rowBase) work items ----------------
__global__ void build_tiles_k(const int* __restrict__ counts, int2* __restrict__ tileDesc,
                              int* __restrict__ nTilesPtr) {
    __shared__ int base[9];
    if (threadIdx.x == 0) {
        int acc = 0;
        #pragma unroll
        for (int e = 0; e < 8; ++e) { base[e] = acc; acc += (counts[e] + 127) >> 7; }
        base[8] = acc; *nTilesPtr = acc;
    }
    __syncthreads();
    #pragma unroll
    for (int e = 0; e < 8; ++e) {
        int nt = base[e + 1] - base[e];
        if ((int)threadIdx.x < nt)
            tileDesc[base[e] + threadIdx.x] = make_int2(e, (int)threadIdx.x * 128);
    }
}

// ---------------- grouped GEMM, double-buffered prefetch + fused epilogue ----------------
// grid: (tile<=135, hTile=16), block 256 (4 waves, 2x2). XOR-swizzled LDS, 2 LDS buffers.
#define GPTR(p) (const __attribute__((address_space(1))) void*)(p)
#define LPTR(p) (__attribute__((address_space(3))) void*)(p)

__global__ __launch_bounds__(256) void moe_gemm_k(
    const unsigned short* __restrict__ xb, const unsigned short* __restrict__ w1t,
    const float* __restrict__ b1, const float* __restrict__ w2sum,
    const int* __restrict__ counts, const int* __restrict__ ptok,
    const float* __restrict__ pscore, const int2* __restrict__ tileDesc,
    const int* __restrict__ nTilesPtr, float* __restrict__ s_partial) {

    int nTiles = *nTilesPtr;
    if ((int)blockIdx.x >= nTiles) return;
    int2 td = tileDesc[blockIdx.x];
    int e = td.x, rowBase = td.y;
    int n_e = counts[e];
    int hBase = blockIdx.y * 128;

    __shared__ unsigned short A_s[2][128 * 32];   // [buf][row*32+k], chunk-swizzled
    __shared__ unsigned short B_s[2][128 * 32];
    __shared__ int   tokLds[128];
    __shared__ float scoreLds[128];

    int tid = threadIdx.x;
    int wave = tid >> 6, lane = tid & 63;

    if (tid < 128) {
        int r = rowBase + tid;
        bool valid = r < n_e;
        tokLds[tid]   = valid ? ptok[e * T_TOK + r]   : 0;
        scoreLds[tid] = valid ? pscore[e * T_TOK + r] : 0.f;
    }
    __syncthreads();

    // staging: 512 16B chunks per matrix; slot c holds (row=c>>2, piece=(c&3)^((row>>1)&3))
    int c0 = wave * 128 + lane;
    int c1 = c0 + 64;
    int rA0 = c0 >> 2, rA1 = c1 >> 2;
    int p0 = ((c0 & 3) ^ ((rA0 >> 1) & 3)) * 8;
    int p1 = ((c1 & 3) ^ ((rA1 >> 1) & 3)) * 8;
    const unsigned short* gA0 = xb + (size_t)tokLds[rA0] * DIM + p0;
    const unsigned short* gA1 = xb + (size_t)tokLds[rA1] * DIM + p1;
    const unsigned short* gB0 = w1t + ((size_t)e * HID + hBase + rA0) * DIM + p0;
    const unsigned short* gB1 = w1t + ((size_t)e * HID + hBase + rA1) * DIM + p1;
    int lo0 = c0 * 8, lo1 = c1 * 8;

    int wm = wave >> 1, wn = wave & 1;
    int quad = lane >> 4, col = lane & 15;
    int swz = (quad ^ ((col >> 1) & 3)) * 8;
    int abOff = (wm * 64 + col) * 32 + swz;
    int bbOff = (wn * 64 + col) * 32 + swz;

    f32x4 acc[4][4];
    #pragma unroll
    for (int m = 0; m < 4; ++m)
        #pragma unroll
        for (int n = 0; n < 4; ++n)
            acc[m][n] = (f32x4){0.f, 0.f, 0.f, 0.f};

    // prefetch k-slice 0 into buffer 0
    __builtin_amdgcn_global_load_lds(GPTR(gA0), LPTR(&A_s[0][lo0]), 16, 0, 0);
    __builtin_amdgcn_global_load_lds(GPTR(gA1), LPTR(&A_s[0][lo1]), 16, 0, 0);
    __builtin_amdgcn_global_load_lds(GPTR(gB0), LPTR(&B_s[0][lo0]), 16, 0, 0);
    __builtin_amdgcn_global_load_lds(GPTR(gB1), LPTR(&B_s[0][lo1]), 16, 0, 0);

    for (int kk = 0; kk < 16; ++kk) {
        int p = kk & 1;
        __syncthreads();   // buf[p] ready (vmcnt drain); buf[p^1] readers from kk-1 done
        if (kk < 15) {
            int ko = (kk + 1) * 32;
            __builtin_amdgcn_global_load_lds(GPTR(gA0 + ko), LPTR(&A_s[p ^ 1][lo0]), 16, 0, 0);
            __builtin_amdgcn_global_load_lds(GPTR(gA1 + ko), LPTR(&A_s[p ^ 1][lo1]), 16, 0, 0);
            __builtin_amdgcn_global_load_lds(GPTR(gB0 + ko), LPTR(&B_s[p ^ 1][lo0]), 16, 0, 0);
            __builtin_amdgcn_global_load_lds(GPTR(gB1 + ko), LPTR(&B_s[p ^ 1][lo1]), 16, 0, 0);
        }
        const unsigned short* aBase = &A_s[p][abOff];
        const unsigned short* bBase = &B_s[p][bbOff];
        short8 af[4], bf[4];
        #pragma unroll
        for (int m = 0; m < 4; ++m) af[m] = *(const short8*)(aBase + m * 16 * 32);
        #pragma unroll
        for (int n = 0; n < 4; ++n) bf[n] = *(const short8*)(bBase + n * 16 * 32);
        #pragma unroll
        for (int m = 0; m < 4; ++m)
            #pragma unroll
            for (int n = 0; n < 4; ++n)
                acc[m][n] = __builtin_amdgcn_mfma_f32_16x16x32_bf16(af[m], bf[n], acc[m][n], 0, 0, 0);
    }

    // epilogue: val = gelu(acc + b1[h]) * w2sum[h]; reduce over h; atomicAdd score*partial
    const float* b1e = b1 + e * HID;
    const float* w2e = w2sum + e * HID;
    float bias[4], wsum[4];
    #pragma unroll
    for (int n = 0; n < 4; ++n) {
        int h = hBase + wn * 64 + n * 16 + col;
        bias[n] = b1e[h];
        wsum[n] = w2e[h];
    }
    #pragma unroll
    for (int m = 0; m < 4; ++m) {
        float rp0 = 0.f, rp1 = 0.f, rp2 = 0.f, rp3 = 0.f;
        #pragma unroll
        for (int n = 0; n < 4; ++n) {
            float v, g;
            v = acc[m][n][0] + bias[n]; g = 0.5f * v * (1.f + erff(v * 0.70710678118f)); rp0 += g * wsum[n];
            v = acc[m][n][1] + bias[n]; g = 0.5f * v * (1.f + erff(v * 0.70710678118f)); rp1 += g * wsum[n];
            v = acc[m][n][2] + bias[n]; g = 0.5f * v * (1.f + erff(v * 0.70710678118f)); rp2 += g * wsum[n];
            v = acc[m][n][3] + bias[n]; g = 0.5f * v * (1.f + erff(v * 0.70710678118f)); rp3 += g * wsum[n];
        }
        #pragma unroll
        for (int off = 8; off >= 1; off >>= 1) {
            rp0 += __shfl_xor(rp0, off);
            rp1 += __shfl_xor(rp1, off);
            rp2 += __shfl_xor(rp2, off);
            rp3 += __shfl_xor(rp3, off);
        }
        if (col < 4) {
            float mine = (col == 0) ? rp0 : (col == 1) ? rp1 : (col == 2) ? rp2 : rp3;
            int rl = wm * 64 + m * 16 + quad * 4 + col;
            int r = rowBase + rl;
            if (r < n_e)
                atomicAdd(&s_partial[tokLds[rl]], scoreLds[rl] * mine);
        }
    }
}

// ---------------- per-batch log_softmax over seq ----------------
__global__ void lsm_k(const float* __restrict__ s, float* __restrict__ out) {
    int b = blockIdx.x, tid = threadIdx.x;
    int wave = tid >> 6, lane = tid & 63;
    __shared__ float red[4];
    const float* sp = s + (size_t)b * SEQ;
    float v[4];
    #pragma unroll
    for (int i = 0; i < 4; ++i) v[i] = sp[tid + i * 256];
    float m = fmaxf(fmaxf(v[0], v[1]), fmaxf(v[2], v[3]));
    #pragma unroll
    for (int off = 32; off >= 1; off >>= 1) m = fmaxf(m, __shfl_xor(m, off));
    if (lane == 0) red[wave] = m;
    __syncthreads();
    m = fmaxf(fmaxf(red[0], red[1]), fmaxf(red[2], red[3]));
    __syncthreads();
    float t = 0.f;
    #pragma unroll
    for (int i = 0; i < 4; ++i) t += expf(v[i] - m);
    #pragma unroll
    for (int off = 32; off >= 1; off >>= 1) t += __shfl_xor(t, off);
    if (lane == 0) red[wave] = t;
    __syncthreads();
    t = red[0] + red[1] + red[2] + red[3];
    float L = m + logf(t);
    #pragma unroll
    for (int i = 0; i < 4; ++i) out[(size_t)b * SEQ + tid + i * 256] = v[i] - L;
}

extern "C" void kernel_launch(void* const* d_in, const int* in_sizes, int n_in,
                              void* d_out, int out_size, void* d_ws, size_t ws_size,
                              hipStream_t stream) {
    const float* x  = (const float*)d_in[0];
    const float* gw = (const float*)d_in[1];
    const float* gb = (const float*)d_in[2];
    const float* w1 = (const float*)d_in[3];
    const float* b1 = (const float*)d_in[4];
    const float* w2 = (const float*)d_in[5];
    const float* b2 = (const float*)d_in[6];
    float* out = (float*)d_out;

    char* ws = (char*)d_ws;
    int*   counts    = (int*)  (ws + 0);
    int*   nTilesPtr = (int*)  (ws + 64);
    int2*  tileDesc  = (int2*) (ws + 128);
    float* b2sum     = (float*)(ws + 1280);
    float* s_partial = (float*)(ws + 1536);
    float* w2sum     = (float*)(ws + 34304);
    int*   ptok      = (int*)  (ws + 99840);
    float* pscore    = (float*)(ws + 361984);
    int*   eidx      = (int*)  (ws + 624128);
    float* esc0      = (float*)(ws + 656896);
    float* esc1      = (float*)(ws + 689664);
    unsigned short* xb  = (unsigned short*)(ws + 722432);    // 8 MB
    unsigned short* w1t = (unsigned short*)(ws + 9111040);   // 16 MB

    hipMemsetAsync(counts, 0, NEXP * sizeof(int), stream);
    w2b2_k<<<NEXP * HID / 4 + 1, 256, 0, stream>>>(w2, b2, w2sum, b2sum);
    transpose_w1_k<<<dim3(DIM / 64, HID / 64, NEXP), 256, 0, stream>>>(w1, w1t);
    gate2_k<<<T_TOK / 4, 256, 0, stream>>>(x, gw, gb, b2sum, xb, eidx, esc0, esc1, s_partial);
    route_k<<<NEXP, 1024, 0, stream>>>(eidx, esc0, esc1, counts, ptok, pscore);
    build_tiles_k<<<1, 128, 0, stream>>>(counts, tileDesc, nTilesPtr);
    moe_gemm_k<<<dim3(135, 16), 256, 0, stream>>>(xb, w1t, b1, w2sum, counts, ptok, pscore,
                                                  tileDesc, nTilesPtr, s_partial);
    lsm_k<<<NBAT, 256, 0, stream>>>(s_partial, out);
}

// Round 5
// 213.662 us; speedup vs baseline: 1.0961x; 1.0961x over previous
//
#include <hip/hip_runtime.h>
#include <hip/hip_bf16.h>
#include <math.h>

// Problem constants
#define T_TOK 8192   // B*S tokens
#define DIM   512    // D
#define NEXP  8      // E
#define HID   2048   // H
#define NBAT  8      // B
#define SEQ   1024   // S

typedef short  short8 __attribute__((ext_vector_type(8)));
typedef float  f32x4  __attribute__((ext_vector_type(4)));

__device__ __forceinline__ unsigned short f2bf(float f) {
    union { float f; unsigned int u; } v; v.f = f;
    unsigned int u = v.u;
    unsigned int r = u + 0x7FFFu + ((u >> 16) & 1u);  // RNE
    return (unsigned short)(r >> 16);
}

// tanh-approx gelu via single v_exp_f32: v * sigmoid(1.59577*(v + 0.044715 v^3))
__device__ __forceinline__ float gelu_f(float v) {
    float v2 = v * v;
    float w = v * (-2.302344f - 0.102955f * v2);   // -log2(e)*1.59577*(1 + 0.044715 v^2)
    return v / (1.f + __builtin_amdgcn_exp2f(w));
}

// ---------------- fused prep: w1 transpose->bf16, w2sum, b2sum, zero counts ----------------
// grid: 2048 transpose blocks + 4096 w2sum blocks + 1 (b2sum + counts)
__global__ void prep_k(const float* __restrict__ w1, unsigned short* __restrict__ w1t,
                       const float* __restrict__ w2, const float* __restrict__ b2,
                       float* __restrict__ w2sum, float* __restrict__ b2sum,
                       int* __restrict__ counts) {
    int bid = blockIdx.x;
    int tid = threadIdx.x;
    int wave = tid >> 6, lane = tid & 63;
    if (bid < 2048) {
        // ---- w1 [E][D][H] fp32 -> w1t [E][H][D] bf16 ----
        __shared__ unsigned short tile[64][65];
        int e = bid >> 8, r = bid & 255;
        int d0 = (r & 7) * 64, h0 = (r >> 3) * 64;
        const float* src = w1 + (size_t)e * DIM * HID;
        #pragma unroll
        for (int pass = 0; pass < 4; ++pass) {
            int dr = pass * 16 + (tid >> 4);
            int hc = (tid & 15) * 4;
            float4 v = *(const float4*)(src + (size_t)(d0 + dr) * HID + h0 + hc);
            tile[hc + 0][dr] = f2bf(v.x);
            tile[hc + 1][dr] = f2bf(v.y);
            tile[hc + 2][dr] = f2bf(v.z);
            tile[hc + 3][dr] = f2bf(v.w);
        }
        __syncthreads();
        unsigned short* dst = w1t + (size_t)e * HID * DIM;
        #pragma unroll
        for (int pass = 0; pass < 4; ++pass) {
            int hr = pass * 16 + (tid >> 4);
            int dc = (tid & 15) * 4;
            ushort4 o;
            o.x = tile[hr][dc];     o.y = tile[hr][dc + 1];
            o.z = tile[hr][dc + 2]; o.w = tile[hr][dc + 3];
            *(ushort4*)(dst + (size_t)(h0 + hr) * DIM + d0 + dc) = o;
        }
    } else if (bid < 2048 + 4096) {
        int row = (bid - 2048) * 4 + wave;
        const float* p = w2 + (size_t)row * DIM;
        float4 a = *(const float4*)(p + lane * 4);
        float4 b = *(const float4*)(p + 256 + lane * 4);
        float s = a.x + a.y + a.z + a.w + b.x + b.y + b.z + b.w;
        #pragma unroll
        for (int off = 32; off >= 1; off >>= 1) s += __shfl_xor(s, off);
        if (lane == 0) w2sum[row] = s;
    } else {
        if (tid < 8) counts[tid] = 0;
        for (int r = wave; r < NEXP; r += 4) {
            const float* p = b2 + (size_t)r * DIM;
            float s = 0.f;
            for (int i = lane; i < DIM; i += 64) s += p[i];
            #pragma unroll
            for (int off = 32; off >= 1; off >>= 1) s += __shfl_xor(s, off);
            if (lane == 0) b2sum[r] = s;
        }
    }
}

// ---------------- gating + fused x->bf16 cast: NO atomics ----------------
__global__ void gate2_k(const float* __restrict__ x, const float* __restrict__ gw,
                        const float* __restrict__ gb, const float* __restrict__ b2sum,
                        unsigned short* __restrict__ xb,
                        int* __restrict__ eidx, float* __restrict__ esc0,
                        float* __restrict__ esc1, float* __restrict__ s_partial) {
    int wave = threadIdx.x >> 6, lane = threadIdx.x & 63;
    int t = blockIdx.x * 4 + wave;
    const float* xp = x + (size_t)t * DIM;
    unsigned short* xbp = xb + (size_t)t * DIM;
    float acc[8] = {0, 0, 0, 0, 0, 0, 0, 0};
    #pragma unroll
    for (int it = 0; it < 8; ++it) {
        int d = it * 64 + lane;
        float xv = xp[d];
        xbp[d] = f2bf(xv);
        float4 g0 = *(const float4*)(gw + d * 8);
        float4 g1 = *(const float4*)(gw + d * 8 + 4);
        acc[0] += xv * g0.x; acc[1] += xv * g0.y; acc[2] += xv * g0.z; acc[3] += xv * g0.w;
        acc[4] += xv * g1.x; acc[5] += xv * g1.y; acc[6] += xv * g1.z; acc[7] += xv * g1.w;
    }
    #pragma unroll
    for (int e = 0; e < 8; ++e) {
        float s = acc[e];
        #pragma unroll
        for (int off = 32; off >= 1; off >>= 1) s += __shfl_xor(s, off);
        acc[e] = s + gb[e];
    }
    float v0 = -1e30f, v1 = -1e30f; int i0 = 0, i1 = 0;
    #pragma unroll
    for (int e = 0; e < 8; ++e) {
        float v = acc[e];
        if (v > v0) { v1 = v0; i1 = i0; v0 = v; i0 = e; }
        else if (v > v1) { v1 = v; i1 = e; }
    }
    float e1 = expf(v1 - v0);
    float inv = 1.f / (1.f + e1);
    float s0 = inv, s1 = e1 * inv;
    if (lane == 0) {
        eidx[t] = i0 | (i1 << 4);
        esc0[t] = s0;
        esc1[t] = s1;
        s_partial[t] = s0 * b2sum[i0] + s1 * b2sum[i1];
    }
}

// ---------------- routing: ballot-rank within wave, LDS across waves, 8 atomics/block ----------------
__global__ __launch_bounds__(1024) void route_k(
    const int* __restrict__ eidx, const float* __restrict__ esc0,
    const float* __restrict__ esc1, int* __restrict__ counts,
    int* __restrict__ ptok, float* __restrict__ pscore) {
    int tid = threadIdx.x;
    int t = blockIdx.x * 1024 + tid;
    int wv = tid >> 6, lane = tid & 63;
    int pk = eidx[t];
    int i0 = pk & 0xf, i1 = (pk >> 4) & 0xf;
    float s0 = esc0[t], s1 = esc1[t];

    __shared__ int waveCnt[16][8];
    __shared__ int waveBase[16][8];

    unsigned long long m0[8], m1[8];
    #pragma unroll
    for (int e = 0; e < 8; ++e) {
        m0[e] = __ballot(i0 == e);
        m1[e] = __ballot(i1 == e);
    }
    if (lane < 8) {
        int c = 0;
        #pragma unroll
        for (int e = 0; e < 8; ++e)
            if (lane == e) c = __popcll(m0[e]) + __popcll(m1[e]);
        waveCnt[wv][lane] = c;
    }
    __syncthreads();
    if (tid < 8) {
        int e = tid;
        int total = 0;
        #pragma unroll
        for (int w = 0; w < 16; ++w) total += waveCnt[w][e];
        int base = atomicAdd(&counts[e], total);
        int run = base;
        #pragma unroll
        for (int w = 0; w < 16; ++w) {
            waveBase[w][e] = run;
            run += waveCnt[w][e];
        }
    }
    __syncthreads();

    unsigned long long lt = (1ULL << lane) - 1ULL;
    int slot0 = 0, slot1 = 0;
    #pragma unroll
    for (int e = 0; e < 8; ++e) {
        if (i0 == e) slot0 = waveBase[wv][e] + __popcll(m0[e] & lt);
        if (i1 == e) slot1 = waveBase[wv][e] + __popcll(m0[e]) + __popcll(m1[e] & lt);
    }
    ptok[i0 * T_TOK + slot0] = t;  pscore[i0 * T_TOK + slot0] = s0;
    ptok[i1 * T_TOK + slot1] = t;  pscore[i1 * T_TOK + slot1] = s1;
}

// ---------------- grouped GEMM, BK=64 single-buffer + fused epilogue ----------------
// grid: (tile<=135, hTile=16), block 256 (4 waves, 2x2). 8-chunk XOR-swizzled LDS.
#define GPTR(p) (const __attribute__((address_space(1))) void*)(p)
#define LPTR(p) (__attribute__((address_space(3))) void*)(p)

__global__ __launch_bounds__(256) void moe_gemm_k(
    const unsigned short* __restrict__ xb, const unsigned short* __restrict__ w1t,
    const float* __restrict__ b1, const float* __restrict__ w2sum,
    const int* __restrict__ counts, const int* __restrict__ ptok,
    const float* __restrict__ pscore, float* __restrict__ s_partial) {

    // derive (expert, rowBase) from counts prefix — no tile-desc kernel needed
    int bx = blockIdx.x;
    int e = 8, rowBase = 0, accT = 0;
    #pragma unroll
    for (int i = 0; i < 8; ++i) {
        int nt = (counts[i] + 127) >> 7;
        if (e == 8 && bx < accT + nt) { e = i; rowBase = (bx - accT) * 128; }
        accT += nt;
    }
    if (e == 8) return;
    int n_e = counts[e];
    int hBase = blockIdx.y * 128;

    __shared__ unsigned short A_s[128 * 64];   // [row][k0..63], chunk-swizzled
    __shared__ unsigned short B_s[128 * 64];
    __shared__ int   tokLds[128];
    __shared__ float scoreLds[128];

    int tid = threadIdx.x;
    int wave = tid >> 6, lane = tid & 63;

    if (tid < 128) {
        int r = rowBase + tid;
        bool valid = r < n_e;
        tokLds[tid]   = valid ? ptok[e * T_TOK + r]   : 0;
        scoreLds[tid] = valid ? pscore[e * T_TOK + r] : 0.f;
    }
    __syncthreads();

    // staging: 1024 16B chunks per matrix; slot c -> (row=c>>3, pos=c&7, piece=pos^(row&7))
    const unsigned short* gA[4];
    const unsigned short* gB[4];
    int lo[4];
    #pragma unroll
    for (int i = 0; i < 4; ++i) {
        int c = (i * 4 + wave) * 64 + lane;
        int row = c >> 3, pos = c & 7;
        int j = (pos ^ (row & 7)) * 8;          // ushort offset of global piece
        gA[i] = xb + (size_t)tokLds[row] * DIM + j;
        gB[i] = w1t + ((size_t)e * HID + hBase + row) * DIM + j;
        lo[i] = c * 8;
    }

    int wm = wave >> 1, wn = wave & 1;
    int quad = lane >> 4, col = lane & 15;

    f32x4 acc[4][4];
    #pragma unroll
    for (int m = 0; m < 4; ++m)
        #pragma unroll
        for (int n = 0; n < 4; ++n)
            acc[m][n] = (f32x4){0.f, 0.f, 0.f, 0.f};

    for (int kk = 0; kk < 8; ++kk) {
        __syncthreads();                        // all reads of LDS from prev iter done
        int ko = kk * 64;
        #pragma unroll
        for (int i = 0; i < 4; ++i) {
            __builtin_amdgcn_global_load_lds(GPTR(gA[i] + ko), LPTR(&A_s[lo[i]]), 16, 0, 0);
            __builtin_amdgcn_global_load_lds(GPTR(gB[i] + ko), LPTR(&B_s[lo[i]]), 16, 0, 0);
        }
        __syncthreads();                        // vmcnt drain: tile resident
        #pragma unroll
        for (int kh = 0; kh < 2; ++kh) {
            int swz = (((kh << 2) | quad) ^ (col & 7)) * 8;
            const unsigned short* aB = A_s + (wm * 64 + col) * 64 + swz;
            const unsigned short* bB = B_s + (wn * 64 + col) * 64 + swz;
            short8 af[4], bf[4];
            #pragma unroll
            for (int m = 0; m < 4; ++m) af[m] = *(const short8*)(aB + m * 16 * 64);
            #pragma unroll
            for (int n = 0; n < 4; ++n) bf[n] = *(const short8*)(bB + n * 16 * 64);
            #pragma unroll
            for (int m = 0; m < 4; ++m)
                #pragma unroll
                for (int n = 0; n < 4; ++n)
                    acc[m][n] = __builtin_amdgcn_mfma_f32_16x16x32_bf16(af[m], bf[n], acc[m][n], 0, 0, 0);
        }
    }

    // epilogue: val = gelu(acc + b1[h]) * w2sum[h]; reduce over h; atomicAdd score*partial
    const float* b1e = b1 + e * HID;
    const float* w2e = w2sum + e * HID;
    float bias[4], wsum[4];
    #pragma unroll
    for (int n = 0; n < 4; ++n) {
        int h = hBase + wn * 64 + n * 16 + col;
        bias[n] = b1e[h];
        wsum[n] = w2e[h];
    }
    #pragma unroll
    for (int m = 0; m < 4; ++m) {
        float rp0 = 0.f, rp1 = 0.f, rp2 = 0.f, rp3 = 0.f;
        #pragma unroll
        for (int n = 0; n < 4; ++n) {
            rp0 += gelu_f(acc[m][n][0] + bias[n]) * wsum[n];
            rp1 += gelu_f(acc[m][n][1] + bias[n]) * wsum[n];
            rp2 += gelu_f(acc[m][n][2] + bias[n]) * wsum[n];
            rp3 += gelu_f(acc[m][n][3] + bias[n]) * wsum[n];
        }
        #pragma unroll
        for (int off = 8; off >= 1; off >>= 1) {
            rp0 += __shfl_xor(rp0, off);
            rp1 += __shfl_xor(rp1, off);
            rp2 += __shfl_xor(rp2, off);
            rp3 += __shfl_xor(rp3, off);
        }
        if (col < 4) {
            float mine = (col == 0) ? rp0 : (col == 1) ? rp1 : (col == 2) ? rp2 : rp3;
            int rl = wm * 64 + m * 16 + quad * 4 + col;
            int r = rowBase + rl;
            if (r < n_e)
                atomicAdd(&s_partial[tokLds[rl]], scoreLds[rl] * mine);
        }
    }
}

// ---------------- per-batch log_softmax over seq ----------------
__global__ void lsm_k(const float* __restrict__ s, float* __restrict__ out) {
    int b = blockIdx.x, tid = threadIdx.x;
    int wave = tid >> 6, lane = tid & 63;
    __shared__ float red[4];
    const float* sp = s + (size_t)b * SEQ;
    float v[4];
    #pragma unroll
    for (int i = 0; i < 4; ++i) v[i] = sp[tid + i * 256];
    float m = fmaxf(fmaxf(v[0], v[1]), fmaxf(v[2], v[3]));
    #pragma unroll
    for (int off = 32; off >= 1; off >>= 1) m = fmaxf(m, __shfl_xor(m, off));
    if (lane == 0) red[wave] = m;
    __syncthreads();
    m = fmaxf(fmaxf(red[0], red[1]), fmaxf(red[2], red[3]));
    __syncthreads();
    float t = 0.f;
    #pragma unroll
    for (int i = 0; i < 4; ++i) t += expf(v[i] - m);
    #pragma unroll
    for (int off = 32; off >= 1; off >>= 1) t += __shfl_xor(t, off);
    if (lane == 0) red[wave] = t;
    __syncthreads();
    t = red[0] + red[1] + red[2] + red[3];
    float L = m + logf(t);
    #pragma unroll
    for (int i = 0; i < 4; ++i) out[(size_t)b * SEQ + tid + i * 256] = v[i] - L;
}

extern "C" void kernel_launch(void* const* d_in, const int* in_sizes, int n_in,
                              void* d_out, int out_size, void* d_ws, size_t ws_size,
                              hipStream_t stream) {
    const float* x  = (const float*)d_in[0];
    const float* gw = (const float*)d_in[1];
    const float* gb = (const float*)d_in[2];
    const float* w1 = (const float*)d_in[3];
    const float* b1 = (const float*)d_in[4];
    const float* w2 = (const float*)d_in[5];
    const float* b2 = (const float*)d_in[6];
    float* out = (float*)d_out;

    char* ws = (char*)d_ws;
    int*   counts    = (int*)  (ws + 0);
    float* b2sum     = (float*)(ws + 1280);
    float* s_partial = (float*)(ws + 1536);
    float* w2sum     = (float*)(ws + 34304);
    int*   ptok      = (int*)  (ws + 99840);
    float* pscore    = (float*)(ws + 361984);
    int*   eidx      = (int*)  (ws + 624128);
    float* esc0      = (float*)(ws + 656896);
    float* esc1      = (float*)(ws + 689664);
    unsigned short* xb  = (unsigned short*)(ws + 722432);    // 8 MB
    unsigned short* w1t = (unsigned short*)(ws + 9111040);   // 16 MB

    prep_k<<<2048 + 4096 + 1, 256, 0, stream>>>(w1, w1t, w2, b2, w2sum, b2sum, counts);
    gate2_k<<<T_TOK / 4, 256, 0, stream>>>(x, gw, gb, b2sum, xb, eidx, esc0, esc1, s_partial);
    route_k<<<NEXP, 1024, 0, stream>>>(eidx, esc0, esc1, counts, ptok, pscore);
    moe_gemm_k<<<dim3(135, 16), 256, 0, stream>>>(xb, w1t, b1, w2sum, counts, ptok, pscore, s_partial);
    lsm_k<<<NBAT, 256, 0, stream>>>(s_partial, out);
}